// Round 1
// baseline (1948.494 us; speedup 1.0000x reference)
//
#include <hip/hip_runtime.h>
#include <stdint.h>

#define HEADS 8
#define DIM 8
#define HD 64
#define F_IN 128
#define T_SEQ 2048
#define GHID 16

// monotone float -> uint mapping for atomicMax-based float max.
// init value 0u maps below -inf, so memset(0) is a valid "empty" state.
__device__ __forceinline__ unsigned fmap(float f) {
    unsigned u = __float_as_uint(f);
    return (u & 0x80000000u) ? ~u : (u | 0x80000000u);
}
__device__ __forceinline__ float funmap(unsigned u) {
    unsigned b = (u & 0x80000000u) ? (u ^ 0x80000000u) : ~u;
    return __uint_as_float(b);
}

// K1: xp = x @ W_gat  [N,64]; a_src[n,h] = sum_d xp[n,h,d]*att_src[h,d]; same a_dst.
// 256 threads = 4 nodes/block, thread (ln,k): one output element (dot-128).
__global__ __launch_bounds__(256) void k1_xp(
        const float* __restrict__ x, const float* __restrict__ Wg,
        const float* __restrict__ att_s, const float* __restrict__ att_d,
        float* __restrict__ xp, float* __restrict__ a_src, float* __restrict__ a_dst) {
    __shared__ float Wl[F_IN * HD];      // 32 KB
    __shared__ float xs[4][F_IN];        // 2 KB
    __shared__ float atts[HD], attd[HD];
    int t = threadIdx.x;
    for (int i = t * 4; i < F_IN * HD; i += 256 * 4)
        *(float4*)&Wl[i] = *(const float4*)&Wg[i];
    if (t < HD) { atts[t] = att_s[t]; attd[t] = att_d[t]; }
    int n0 = blockIdx.x * 4;
    {
        int ln = t >> 6, k = t & 63;
        *(float2*)&xs[ln][k * 2] = *(const float2*)&x[(size_t)(n0 + ln) * F_IN + k * 2];
    }
    __syncthreads();
    int ln = t >> 6, k = t & 63;
    float acc = 0.f;
    #pragma unroll 8
    for (int f = 0; f < F_IN; ++f) acc += xs[ln][f] * Wl[f * HD + k];
    int n = n0 + ln;
    xp[(size_t)n * HD + k] = acc;
    float ps = acc * atts[k];
    float pd = acc * attd[k];
    #pragma unroll
    for (int off = 1; off < 8; off <<= 1) {
        ps += __shfl_xor(ps, off);
        pd += __shfl_xor(pd, off);
    }
    if ((k & 7) == 0) {
        a_src[n * HEADS + (k >> 3)] = ps;
        a_dst[n * HEADS + (k >> 3)] = pd;
    }
}

// K2: per edge, alpha = leakyrelu(a_src[src]+a_dst[dst]); atomic segment-max into mu[dst][h].
__global__ __launch_bounds__(256) void k2_max(
        const int* __restrict__ ei, int E, int Etot,
        const float* __restrict__ a_src, const float* __restrict__ a_dst,
        unsigned* __restrict__ mu) {
    int t = blockIdx.x * 256 + threadIdx.x;
    if (t >= Etot) return;
    int s, d;
    if (t < E) { s = ei[t]; d = ei[E + t]; } else { s = d = t - E; }
    const float4* ap = (const float4*)(a_src + (size_t)s * 8);
    const float4* dp = (const float4*)(a_dst + (size_t)d * 8);
    float4 s0 = ap[0], s1 = ap[1];
    float4 d0 = dp[0], d1 = dp[1];
    float al[8] = {s0.x + d0.x, s0.y + d0.y, s0.z + d0.z, s0.w + d0.w,
                   s1.x + d1.x, s1.y + d1.y, s1.z + d1.z, s1.w + d1.w};
    unsigned* mb = mu + (size_t)d * 8;
    #pragma unroll
    for (int h = 0; h < 8; ++h) {
        float a = al[h];
        a = a > 0.f ? a : 0.2f * a;
        atomicMax(&mb[h], fmap(a));
    }
}

// K3: denom[dst][h] += exp(alpha - m[dst][h])
__global__ __launch_bounds__(256) void k3_den(
        const int* __restrict__ ei, int E, int Etot,
        const float* __restrict__ a_src, const float* __restrict__ a_dst,
        const unsigned* __restrict__ mu, float* __restrict__ denom) {
    int t = blockIdx.x * 256 + threadIdx.x;
    if (t >= Etot) return;
    int s, d;
    if (t < E) { s = ei[t]; d = ei[E + t]; } else { s = d = t - E; }
    const float4* ap = (const float4*)(a_src + (size_t)s * 8);
    const float4* dp = (const float4*)(a_dst + (size_t)d * 8);
    float4 s0 = ap[0], s1 = ap[1];
    float4 d0 = dp[0], d1 = dp[1];
    float al[8] = {s0.x + d0.x, s0.y + d0.y, s0.z + d0.z, s0.w + d0.w,
                   s1.x + d1.x, s1.y + d1.y, s1.z + d1.z, s1.w + d1.w};
    const unsigned* mb = mu + (size_t)d * 8;
    float* db = denom + (size_t)d * 8;
    #pragma unroll
    for (int h = 0; h < 8; ++h) {
        float a = al[h];
        a = a > 0.f ? a : 0.2f * a;
        float m = funmap(mb[h]);
        atomicAdd(&db[h], __expf(a - m));
    }
}

// K4: agg[dst][k] += xp[src][k] * w(edge, head=k>>3).  64 lanes per edge.
__global__ __launch_bounds__(256) void k4_agg(
        const int* __restrict__ ei, int E, int Etot,
        const float* __restrict__ a_src, const float* __restrict__ a_dst,
        const unsigned* __restrict__ mu, const float* __restrict__ denom,
        const float* __restrict__ xp, float* __restrict__ agg) {
    int t = blockIdx.x * 256 + threadIdx.x;
    int e = t >> 6;
    if (e >= Etot) return;
    int k = t & 63, h = k >> 3;
    int s, d;
    if (e < E) { s = ei[e]; d = ei[E + e]; } else { s = d = e - E; }
    float a = a_src[(size_t)s * 8 + h] + a_dst[(size_t)d * 8 + h];
    a = a > 0.f ? a : 0.2f * a;
    float m = funmap(mu[(size_t)d * 8 + h]);
    float den = denom[(size_t)d * 8 + h];
    float w = __expf(a - m) / (den + 1e-16f);
    float v = xp[(size_t)s * 64 + k];
    atomicAdd(&agg[(size_t)d * 64 + k], v * w);
}

// K5: gi[n][g] = b_ih[g] + sum_f relu(agg[n][f]+b_gat[f]) * W_ih[g][f]
// 16 nodes per 256-thread block; W_ih (48x64) LDS-staged with +1 pad.
__global__ __launch_bounds__(256) void k5_gi(
        const float* __restrict__ agg, const float* __restrict__ b_gat,
        const float* __restrict__ W_ih, const float* __restrict__ b_ih,
        float* __restrict__ gi) {
    __shared__ float Wl[48 * 65];
    __shared__ float fl[16][65];
    __shared__ float bg[64], bi[48];
    int t = threadIdx.x;
    for (int i = t; i < 48 * 64; i += 256) Wl[(i >> 6) * 65 + (i & 63)] = W_ih[i];
    if (t < 64) bg[t] = b_gat[t];
    if (t < 48) bi[t] = b_ih[t];
    int n0 = blockIdx.x * 16;
    __syncthreads();
    for (int i = t; i < 16 * 64; i += 256) {
        int ln = i >> 6, k = i & 63;
        float v = agg[(size_t)(n0 + ln) * 64 + k] + bg[k];
        fl[ln][k] = v > 0.f ? v : 0.f;
    }
    __syncthreads();
    for (int o = t; o < 16 * 48; o += 256) {
        int ln = o / 48, g = o % 48;
        float acc = bi[g];
        #pragma unroll 8
        for (int f = 0; f < 64; ++f) acc += fl[ln][f] * Wl[g * 65 + f];
        gi[(size_t)(n0 + ln) * 48 + g] = acc;
    }
}

// K6: GRU scan over T=2048 per batch element. 1 block (1 wave) per batch.
// Lane j<16 computes all 3 gates of hidden unit j; W_hh rows in registers.
// gi staged in LDS chunks of 32 steps.
__global__ __launch_bounds__(64) void k6_gru(
        const float* __restrict__ gi, const float* __restrict__ W_hh,
        const float* __restrict__ b_hh, const float* __restrict__ W_lin,
        const float* __restrict__ b_lin, float* __restrict__ out, int B) {
    __shared__ __align__(16) float h[GHID];
    __shared__ __align__(16) float gch[32][48];
    int b = blockIdx.x;
    int t = threadIdx.x;
    float wr[16], wz[16], wn[16];
    float bhr = 0.f, bhz = 0.f, bhn = 0.f;
    if (t < GHID) {
        #pragma unroll
        for (int k = 0; k < 16; ++k) {
            wr[k] = W_hh[t * 16 + k];
            wz[k] = W_hh[(16 + t) * 16 + k];
            wn[k] = W_hh[(32 + t) * 16 + k];
        }
        bhr = b_hh[t]; bhz = b_hh[16 + t]; bhn = b_hh[32 + t];
        h[t] = 0.f;
    }
    const float* gib = gi + (size_t)b * T_SEQ * 48;
    for (int c = 0; c < T_SEQ / 32; ++c) {
        __syncthreads();  // previous chunk fully consumed, h written
        #pragma unroll
        for (int i = 0; i < 6; ++i) {
            int idx = (i * 64 + t) * 4;
            *(float4*)&gch[0][idx] = *(const float4*)&gib[(size_t)c * 1536 + idx];
        }
        __syncthreads();
        for (int tc = 0; tc < 32; ++tc) {
            float hnew = 0.f;
            if (t < GHID) {
                float4 ha = *(const float4*)&h[0];
                float4 hb = *(const float4*)&h[4];
                float4 hc = *(const float4*)&h[8];
                float4 hd = *(const float4*)&h[12];
                float hv[16] = {ha.x, ha.y, ha.z, ha.w, hb.x, hb.y, hb.z, hb.w,
                                hc.x, hc.y, hc.z, hc.w, hd.x, hd.y, hd.z, hd.w};
                float hcur = h[t];
                float r0 = 0.f, r1 = 0.f, r2 = 0.f, r3 = 0.f;
                float z0 = 0.f, z1 = 0.f, z2 = 0.f, z3 = 0.f;
                float n0 = 0.f, n1 = 0.f, n2 = 0.f, n3 = 0.f;
                #pragma unroll
                for (int k = 0; k < 16; k += 4) {
                    r0 += wr[k] * hv[k];   r1 += wr[k+1] * hv[k+1];
                    r2 += wr[k+2] * hv[k+2]; r3 += wr[k+3] * hv[k+3];
                    z0 += wz[k] * hv[k];   z1 += wz[k+1] * hv[k+1];
                    z2 += wz[k+2] * hv[k+2]; z3 += wz[k+3] * hv[k+3];
                    n0 += wn[k] * hv[k];   n1 += wn[k+1] * hv[k+1];
                    n2 += wn[k+2] * hv[k+2]; n3 += wn[k+3] * hv[k+3];
                }
                float ghr = (r0 + r1) + (r2 + r3) + bhr;
                float ghz = (z0 + z1) + (z2 + z3) + bhz;
                float ghn = (n0 + n1) + (n2 + n3) + bhn;
                float ir = gch[tc][t], iz = gch[tc][16 + t], inn = gch[tc][32 + t];
                float r = 1.f / (1.f + __expf(-(ir + ghr)));
                float z = 1.f / (1.f + __expf(-(iz + ghz)));
                float np = inn + r * ghn;
                np = fminf(fmaxf(np, -30.f), 30.f);
                float e2 = __expf(-2.f * np);
                float nn = (1.f - e2) / (1.f + e2);
                hnew = (1.f - z) * nn + z * hcur;
            }
            __syncthreads();
            if (t < GHID) h[t] = hnew;
            __syncthreads();
        }
    }
    __syncthreads();
    if (t == 0) {
        float acc = b_lin[0];
        #pragma unroll
        for (int k = 0; k < 16; ++k) acc += h[k] * W_lin[k];
        out[b] = acc;
    }
    if (t < GHID) out[B + b * GHID + t] = h[t];
}

extern "C" void kernel_launch(void* const* d_in, const int* in_sizes, int n_in,
                              void* d_out, int out_size, void* d_ws, size_t ws_size,
                              hipStream_t stream) {
    const float* x      = (const float*)d_in[0];
    const int*   ei     = (const int*)d_in[1];
    // d_in[2] edge_attr: unused (edge_dim=None)
    const float* W_gat  = (const float*)d_in[3];
    const float* att_s  = (const float*)d_in[4];
    const float* att_d  = (const float*)d_in[5];
    const float* b_gat  = (const float*)d_in[6];
    const float* W_ih   = (const float*)d_in[7];
    const float* W_hh   = (const float*)d_in[8];
    const float* b_ih   = (const float*)d_in[9];
    const float* b_hh   = (const float*)d_in[10];
    const float* W_lin  = (const float*)d_in[11];
    const float* b_lin  = (const float*)d_in[12];
    float* out = (float*)d_out;

    int N = in_sizes[0] / F_IN;       // 65536
    int E = in_sizes[1] / 2;          // 1048576
    int Etot = E + N;                 // self-loops appended
    int B = N / T_SEQ;                // 32

    float* ws = (float*)d_ws;
    float* xp     = ws;                                   // N*64
    float* a_src  = xp + (size_t)N * 64;                  // N*8
    float* a_dst  = a_src + (size_t)N * 8;                // N*8
    unsigned* mu  = (unsigned*)(a_dst + (size_t)N * 8);   // N*8
    float* denom  = (float*)(mu + (size_t)N * 8);         // N*8
    float* agg    = denom + (size_t)N * 8;                // N*64
    float* gi     = agg + (size_t)N * 64;                 // N*48

    // zero mu + denom + agg (contiguous): 2+2+16 MB
    hipMemsetAsync(mu, 0, ((size_t)N * 8 * 2 + (size_t)N * 64) * sizeof(float), stream);

    k1_xp<<<N / 4, 256, 0, stream>>>(x, W_gat, att_s, att_d, xp, a_src, a_dst);
    k2_max<<<(Etot + 255) / 256, 256, 0, stream>>>(ei, E, Etot, a_src, a_dst, mu);
    k3_den<<<(Etot + 255) / 256, 256, 0, stream>>>(ei, E, Etot, a_src, a_dst, mu, denom);
    {
        long long tot = (long long)Etot * 64;
        int blocks = (int)((tot + 255) / 256);
        k4_agg<<<blocks, 256, 0, stream>>>(ei, E, Etot, a_src, a_dst, mu, denom, xp, agg);
    }
    k5_gi<<<N / 16, 256, 0, stream>>>(agg, b_gat, W_ih, b_ih, gi);
    k6_gru<<<B, 64, 0, stream>>>(gi, W_hh, b_hh, W_lin, b_lin, out, B);
}

// Round 2
// 938.102 us; speedup vs baseline: 2.0771x; 2.0771x over previous
//
#include <hip/hip_runtime.h>
#include <stdint.h>

#define HEADS 8
#define DIM 8
#define HD 64
#define F_IN 128
#define T_SEQ 2048
#define GHID 16

// K1: xp = x @ W_gat  [N,64]; a_src[n,h] = sum_d xp[n,h,d]*att_src[h,d]; same a_dst.
// 256 threads = 4 nodes/block, thread (ln,k): one output element (dot-128).
__global__ __launch_bounds__(256) void k1_xp(
        const float* __restrict__ x, const float* __restrict__ Wg,
        const float* __restrict__ att_s, const float* __restrict__ att_d,
        float* __restrict__ xp, float* __restrict__ a_src, float* __restrict__ a_dst) {
    __shared__ float Wl[F_IN * HD];      // 32 KB
    __shared__ float xs[4][F_IN];        // 2 KB
    __shared__ float atts[HD], attd[HD];
    int t = threadIdx.x;
    for (int i = t * 4; i < F_IN * HD; i += 256 * 4)
        *(float4*)&Wl[i] = *(const float4*)&Wg[i];
    if (t < HD) { atts[t] = att_s[t]; attd[t] = att_d[t]; }
    int n0 = blockIdx.x * 4;
    {
        int ln = t >> 6, k = t & 63;
        *(float2*)&xs[ln][k * 2] = *(const float2*)&x[(size_t)(n0 + ln) * F_IN + k * 2];
    }
    __syncthreads();
    int ln = t >> 6, k = t & 63;
    float acc = 0.f;
    #pragma unroll 8
    for (int f = 0; f < F_IN; ++f) acc += xs[ln][f] * Wl[f * HD + k];
    int n = n0 + ln;
    xp[(size_t)n * HD + k] = acc;
    float ps = acc * atts[k];
    float pd = acc * attd[k];
    #pragma unroll
    for (int off = 1; off < 8; off <<= 1) {
        ps += __shfl_xor(ps, off);
        pd += __shfl_xor(pd, off);
    }
    if ((k & 7) == 0) {
        a_src[n * HEADS + (k >> 3)] = ps;
        a_dst[n * HEADS + (k >> 3)] = pd;
    }
}

// K4 (fused softmax-denom + aggregation, no max-subtraction):
// per edge: e = exp(leakyrelu(a_src[s]+a_dst[d])); denom[d][h] += e;
// agg[d][k] += xp[s][k] * e.   64 lanes per edge.
__global__ __launch_bounds__(256) void k4_agg(
        const int* __restrict__ ei, int E, int Etot,
        const float* __restrict__ a_src, const float* __restrict__ a_dst,
        const float* __restrict__ xp, float* __restrict__ denom,
        float* __restrict__ agg) {
    int t = blockIdx.x * 256 + threadIdx.x;
    int e = t >> 6;
    if (e >= Etot) return;
    int k = t & 63, h = k >> 3;
    int s, d;
    if (e < E) { s = ei[e]; d = ei[E + e]; } else { s = d = e - E; }
    float a = a_src[(size_t)s * 8 + h] + a_dst[(size_t)d * 8 + h];
    a = a > 0.f ? a : 0.2f * a;
    float ew = __expf(a);
    if ((k & 7) == 0) atomicAdd(&denom[(size_t)d * 8 + h], ew);
    float v = xp[(size_t)s * 64 + k];
    atomicAdd(&agg[(size_t)d * 64 + k], v * ew);
}

// K5: gi[n][g] = b_ih[g] + sum_f relu(agg[n][f]/(denom[n][f>>3]+eps) + b_gat[f]) * W_ih[g][f]
__global__ __launch_bounds__(256) void k5_gi(
        const float* __restrict__ agg, const float* __restrict__ denom,
        const float* __restrict__ b_gat,
        const float* __restrict__ W_ih, const float* __restrict__ b_ih,
        float* __restrict__ gi) {
    __shared__ float Wl[48 * 65];
    __shared__ float fl[16][65];
    __shared__ float bg[64], bi[48];
    int t = threadIdx.x;
    for (int i = t; i < 48 * 64; i += 256) Wl[(i >> 6) * 65 + (i & 63)] = W_ih[i];
    if (t < 64) bg[t] = b_gat[t];
    if (t < 48) bi[t] = b_ih[t];
    int n0 = blockIdx.x * 16;
    __syncthreads();
    for (int i = t; i < 16 * 64; i += 256) {
        int ln = i >> 6, k = i & 63;
        int n = n0 + ln;
        float den = denom[(size_t)n * 8 + (k >> 3)] + 1e-16f;
        float v = agg[(size_t)n * 64 + k] / den + bg[k];
        fl[ln][k] = v > 0.f ? v : 0.f;
    }
    __syncthreads();
    for (int o = t; o < 16 * 48; o += 256) {
        int ln = o / 48, g = o % 48;
        float acc = bi[g];
        #pragma unroll 8
        for (int f = 0; f < 64; ++f) acc += fl[ln][f] * Wl[g * 65 + f];
        gi[(size_t)(n0 + ln) * 48 + g] = acc;
    }
}

// K6: GRU scan, 1 wave per batch element. No LDS, no barriers.
// lane l: g = l>>4 (0:r 1:z 2:n 3:dup), t = l&15 (hidden unit).
// Each lane computes one gate-row dot (16 FMA); gate pre-activations are
// exchanged via ds_bpermute (__shfl); h lives in registers, broadcast via
// v_readlane (__shfl with literal lane). gi prefetched 8 steps deep from global.
__global__ __launch_bounds__(64) void k6_gru(
        const float* __restrict__ gi, const float* __restrict__ W_hh,
        const float* __restrict__ b_hh, const float* __restrict__ W_lin,
        const float* __restrict__ b_lin, float* __restrict__ out, int B) {
    int l = threadIdx.x;
    int t = l & 15;
    int g = l >> 4;
    int ge = (g < 3) ? g : 2;          // lanes 48-63 duplicate the n gate
    int b = blockIdx.x;

    float w[16];
    #pragma unroll
    for (int k = 0; k < 16; ++k) w[k] = W_hh[(ge * 16 + t) * 16 + k];
    float bh = b_hh[ge * 16 + t];
    int col = ge * 16 + t;             // 0..47 (dup for lanes 48-63)
    const float* gib = gi + (size_t)b * T_SEQ * 48 + col;

    float hcur = 0.f;
    float hs[16];
    #pragma unroll
    for (int k = 0; k < 16; ++k) hs[k] = 0.f;

    const int PF = 8;
    float ip[PF];
    #pragma unroll
    for (int i = 0; i < PF; ++i) ip[i] = gib[(size_t)i * 48];

    for (int c = 0; c < T_SEQ; c += PF) {
        #pragma unroll
        for (int u = 0; u < PF; ++u) {
            float ig = ip[u];
            int nxt = c + PF + u;
            nxt = nxt < T_SEQ ? nxt : T_SEQ - 1;     // uniform clamp, no branch
            ip[u] = gib[(size_t)nxt * 48];

            float igz = (ge == 2) ? 0.f : ig;        // i added pre-sigmoid for r,z only
            float a0 = 0.f, a1 = 0.f, a2 = 0.f, a3 = 0.f;
            #pragma unroll
            for (int k = 0; k < 16; k += 4) {
                a0 = fmaf(w[k],     hs[k],     a0);
                a1 = fmaf(w[k + 1], hs[k + 1], a1);
                a2 = fmaf(w[k + 2], hs[k + 2], a2);
                a3 = fmaf(w[k + 3], hs[k + 3], a3);
            }
            float pre = (a0 + a1) + (a2 + a3) + bh + igz;

            float rpre = __shfl(pre, t);
            float zpre = __shfl(pre, 16 + t);
            float npre = __shfl(pre, 32 + t);
            float i_n  = __shfl(ig,  32 + t);

            float r = 1.f / (1.f + __expf(-rpre));
            float z = 1.f / (1.f + __expf(-zpre));
            float np = i_n + r * npre;
            np = fminf(fmaxf(np, -15.f), 15.f);
            float e2 = __expf(-2.f * np);
            float nn = (1.f - e2) / (1.f + e2);
            hcur = fmaf(z, hcur - nn, nn);           // (1-z)*n + z*h

            #pragma unroll
            for (int k = 0; k < 16; ++k) hs[k] = __shfl(hcur, k);
        }
    }

    if (l == 0) {
        float acc = b_lin[0];
        #pragma unroll
        for (int k = 0; k < 16; ++k) acc += hs[k] * W_lin[k];
        out[b] = acc;
    }
    if (l < GHID) out[B + b * GHID + l] = hcur;
}

extern "C" void kernel_launch(void* const* d_in, const int* in_sizes, int n_in,
                              void* d_out, int out_size, void* d_ws, size_t ws_size,
                              hipStream_t stream) {
    const float* x      = (const float*)d_in[0];
    const int*   ei     = (const int*)d_in[1];
    // d_in[2] edge_attr: unused (edge_dim=None)
    const float* W_gat  = (const float*)d_in[3];
    const float* att_s  = (const float*)d_in[4];
    const float* att_d  = (const float*)d_in[5];
    const float* b_gat  = (const float*)d_in[6];
    const float* W_ih   = (const float*)d_in[7];
    const float* W_hh   = (const float*)d_in[8];
    const float* b_ih   = (const float*)d_in[9];
    const float* b_hh   = (const float*)d_in[10];
    const float* W_lin  = (const float*)d_in[11];
    const float* b_lin  = (const float*)d_in[12];
    float* out = (float*)d_out;

    int N = in_sizes[0] / F_IN;       // 65536
    int E = in_sizes[1] / 2;          // 1048576
    int Etot = E + N;                 // self-loops appended
    int B = N / T_SEQ;                // 32

    float* ws = (float*)d_ws;
    float* xp     = ws;                                   // N*64
    float* a_src  = xp + (size_t)N * 64;                  // N*8
    float* a_dst  = a_src + (size_t)N * 8;                // N*8
    float* denom  = a_dst + (size_t)N * 8;                // N*8
    float* agg    = denom + (size_t)N * 8;                // N*64
    float* gi     = agg + (size_t)N * 64;                 // N*48

    // zero denom + agg (contiguous): 2 + 16 MB
    hipMemsetAsync(denom, 0, (size_t)N * 72 * sizeof(float), stream);

    k1_xp<<<N / 4, 256, 0, stream>>>(x, W_gat, att_s, att_d, xp, a_src, a_dst);
    {
        long long tot = (long long)Etot * 64;
        int blocks = (int)((tot + 255) / 256);
        k4_agg<<<blocks, 256, 0, stream>>>(ei, E, Etot, a_src, a_dst, xp, denom, agg);
    }
    k5_gi<<<N / 16, 256, 0, stream>>>(agg, denom, b_gat, W_ih, b_ih, gi);
    k6_gru<<<B, 64, 0, stream>>>(gi, W_hh, b_hh, W_lin, b_lin, out, B);
}

// Round 3
// 890.426 us; speedup vs baseline: 2.1883x; 1.0535x over previous
//
#include <hip/hip_runtime.h>
#include <stdint.h>

#define HEADS 8
#define DIM 8
#define HD 64
#define F_IN 128
#define T_SEQ 2048
#define GHID 16

// K1: xp = x @ W_gat  [N,64]; a_src[n,h] = sum_d xp[n,h,d]*att_src[h,d]; same a_dst.
// 256 threads = 4 nodes/block, thread (ln,k): one output element (dot-128).
__global__ __launch_bounds__(256) void k1_xp(
        const float* __restrict__ x, const float* __restrict__ Wg,
        const float* __restrict__ att_s, const float* __restrict__ att_d,
        float* __restrict__ xp, float* __restrict__ a_src, float* __restrict__ a_dst) {
    __shared__ float Wl[F_IN * HD];      // 32 KB
    __shared__ float xs[4][F_IN];        // 2 KB
    __shared__ float atts[HD], attd[HD];
    int t = threadIdx.x;
    for (int i = t * 4; i < F_IN * HD; i += 256 * 4)
        *(float4*)&Wl[i] = *(const float4*)&Wg[i];
    if (t < HD) { atts[t] = att_s[t]; attd[t] = att_d[t]; }
    int n0 = blockIdx.x * 4;
    {
        int ln = t >> 6, k = t & 63;
        *(float2*)&xs[ln][k * 2] = *(const float2*)&x[(size_t)(n0 + ln) * F_IN + k * 2];
    }
    __syncthreads();
    int ln = t >> 6, k = t & 63;
    float acc = 0.f;
    #pragma unroll 8
    for (int f = 0; f < F_IN; ++f) acc += xs[ln][f] * Wl[f * HD + k];
    int n = n0 + ln;
    xp[(size_t)n * HD + k] = acc;
    float ps = acc * atts[k];
    float pd = acc * attd[k];
    #pragma unroll
    for (int off = 1; off < 8; off <<= 1) {
        ps += __shfl_xor(ps, off);
        pd += __shfl_xor(pd, off);
    }
    if ((k & 7) == 0) {
        a_src[n * HEADS + (k >> 3)] = ps;
        a_dst[n * HEADS + (k >> 3)] = pd;
    }
}

// K4 (fused softmax-denom + aggregation, no max-subtraction):
// per edge: e = exp(leakyrelu(a_src[s]+a_dst[d])); denom[d][h] += e;
// agg[d][k] += xp[s][k] * e.   64 lanes per edge.
__global__ __launch_bounds__(256) void k4_agg(
        const int* __restrict__ ei, int E, int Etot,
        const float* __restrict__ a_src, const float* __restrict__ a_dst,
        const float* __restrict__ xp, float* __restrict__ denom,
        float* __restrict__ agg) {
    int t = blockIdx.x * 256 + threadIdx.x;
    int e = t >> 6;
    if (e >= Etot) return;
    int k = t & 63, h = k >> 3;
    int s, d;
    if (e < E) { s = ei[e]; d = ei[E + e]; } else { s = d = e - E; }
    float a = a_src[(size_t)s * 8 + h] + a_dst[(size_t)d * 8 + h];
    a = a > 0.f ? a : 0.2f * a;
    float ew = __expf(a);
    if ((k & 7) == 0) atomicAdd(&denom[(size_t)d * 8 + h], ew);
    float v = xp[(size_t)s * 64 + k];
    atomicAdd(&agg[(size_t)d * 64 + k], v * ew);
}

// K5: gi[n][g] = b_ih[g] + sum_f relu(agg[n][f]/(denom[n][f>>3]+eps) + b_gat[f]) * W_ih[g][f]
__global__ __launch_bounds__(256) void k5_gi(
        const float* __restrict__ agg, const float* __restrict__ denom,
        const float* __restrict__ b_gat,
        const float* __restrict__ W_ih, const float* __restrict__ b_ih,
        float* __restrict__ gi) {
    __shared__ float Wl[48 * 65];
    __shared__ float fl[16][65];
    __shared__ float bg[64], bi[48];
    int t = threadIdx.x;
    for (int i = t; i < 48 * 64; i += 256) Wl[(i >> 6) * 65 + (i & 63)] = W_ih[i];
    if (t < 64) bg[t] = b_gat[t];
    if (t < 48) bi[t] = b_ih[t];
    int n0 = blockIdx.x * 16;
    __syncthreads();
    for (int i = t; i < 16 * 64; i += 256) {
        int ln = i >> 6, k = i & 63;
        int n = n0 + ln;
        float den = denom[(size_t)n * 8 + (k >> 3)] + 1e-16f;
        float v = agg[(size_t)n * 64 + k] / den + bg[k];
        fl[ln][k] = v > 0.f ? v : 0.f;
    }
    __syncthreads();
    for (int o = t; o < 16 * 48; o += 256) {
        int ln = o / 48, g = o % 48;
        float acc = bi[g];
        #pragma unroll 8
        for (int f = 0; f < 64; ++f) acc += fl[ln][f] * Wl[g * 65 + f];
        gi[(size_t)(n0 + ln) * 48 + g] = acc;
    }
}

// K6 v3: GRU scan, 1 wave per batch. NO LDS-path ops in the critical loop.
// Lane l owns unit j=l&15 (4x redundant across lane groups, zero divergence)
// and computes ALL THREE gate dots locally -> no cross-lane gather.
// h is held as 16 wave-uniform values (SGPRs), refreshed per step via
// v_readlane (VALU pipe, low latency). FMAs read h from SGPR src directly.
__global__ __launch_bounds__(64) void k6_gru(
        const float* __restrict__ gi, const float* __restrict__ W_hh,
        const float* __restrict__ b_hh, const float* __restrict__ W_lin,
        const float* __restrict__ b_lin, float* __restrict__ out, int B) {
    int l = threadIdx.x;
    int j = l & 15;
    int b = blockIdx.x;

    float wr[16], wz[16], wn[16];
    #pragma unroll
    for (int k = 0; k < 16; ++k) {
        wr[k] = W_hh[j * 16 + k];
        wz[k] = W_hh[(16 + j) * 16 + k];
        wn[k] = W_hh[(32 + j) * 16 + k];
    }
    float bhr = b_hh[j], bhz = b_hh[16 + j], bhn = b_hh[32 + j];

    const float* gib = gi + (size_t)b * T_SEQ * 48;

    float hcur = 0.f;       // lane j's hidden unit value
    float hs[16];           // wave-uniform copy of h (SGPRs via readlane)
    #pragma unroll
    for (int k = 0; k < 16; ++k) hs[k] = 0.f;

    const int PF = 8;
    float pr[PF], pz[PF], pn[PF];
    #pragma unroll
    for (int i = 0; i < PF; ++i) {
        pr[i] = gib[(size_t)i * 48 + j];
        pz[i] = gib[(size_t)i * 48 + 16 + j];
        pn[i] = gib[(size_t)i * 48 + 32 + j];
    }

    for (int c = 0; c < T_SEQ; c += PF) {
        #pragma unroll
        for (int u = 0; u < PF; ++u) {
            float ir = pr[u], iz = pz[u], inn = pn[u];
            int nxt = c + PF + u;
            nxt = nxt < T_SEQ ? nxt : T_SEQ - 1;     // uniform clamp, no branch
            pr[u] = gib[(size_t)nxt * 48 + j];
            pz[u] = gib[(size_t)nxt * 48 + 16 + j];
            pn[u] = gib[(size_t)nxt * 48 + 32 + j];

            float r0 = 0.f, r1 = 0.f, r2 = 0.f, r3 = 0.f;
            float z0 = 0.f, z1 = 0.f, z2 = 0.f, z3 = 0.f;
            float n0 = 0.f, n1 = 0.f, n2 = 0.f, n3 = 0.f;
            #pragma unroll
            for (int k = 0; k < 16; k += 4) {
                r0 = fmaf(wr[k],     hs[k],     r0);
                r1 = fmaf(wr[k + 1], hs[k + 1], r1);
                r2 = fmaf(wr[k + 2], hs[k + 2], r2);
                r3 = fmaf(wr[k + 3], hs[k + 3], r3);
                z0 = fmaf(wz[k],     hs[k],     z0);
                z1 = fmaf(wz[k + 1], hs[k + 1], z1);
                z2 = fmaf(wz[k + 2], hs[k + 2], z2);
                z3 = fmaf(wz[k + 3], hs[k + 3], z3);
                n0 = fmaf(wn[k],     hs[k],     n0);
                n1 = fmaf(wn[k + 1], hs[k + 1], n1);
                n2 = fmaf(wn[k + 2], hs[k + 2], n2);
                n3 = fmaf(wn[k + 3], hs[k + 3], n3);
            }
            float rpre = ((r0 + r1) + (r2 + r3)) + bhr + ir;
            float zpre = ((z0 + z1) + (z2 + z3)) + bhz + iz;
            float npre = ((n0 + n1) + (n2 + n3)) + bhn;

            float r = 1.f / (1.f + __expf(-rpre));
            float z = 1.f / (1.f + __expf(-zpre));
            float np = inn + r * npre;
            np = fminf(fmaxf(np, -15.f), 15.f);
            float e2 = __expf(-2.f * np);
            float nn = (1.f - e2) / (1.f + e2);
            hcur = fmaf(z, hcur - nn, nn);           // (1-z)*n + z*h

            #pragma unroll
            for (int k = 0; k < 16; ++k)
                hs[k] = __int_as_float(
                    __builtin_amdgcn_readlane(__float_as_int(hcur), k));
        }
    }

    if (l == 0) {
        float acc = b_lin[0];
        #pragma unroll
        for (int k = 0; k < 16; ++k) acc += hs[k] * W_lin[k];
        out[b] = acc;
    }
    if (l < GHID) out[B + b * GHID + l] = hcur;
}

extern "C" void kernel_launch(void* const* d_in, const int* in_sizes, int n_in,
                              void* d_out, int out_size, void* d_ws, size_t ws_size,
                              hipStream_t stream) {
    const float* x      = (const float*)d_in[0];
    const int*   ei     = (const int*)d_in[1];
    // d_in[2] edge_attr: unused (edge_dim=None)
    const float* W_gat  = (const float*)d_in[3];
    const float* att_s  = (const float*)d_in[4];
    const float* att_d  = (const float*)d_in[5];
    const float* b_gat  = (const float*)d_in[6];
    const float* W_ih   = (const float*)d_in[7];
    const float* W_hh   = (const float*)d_in[8];
    const float* b_ih   = (const float*)d_in[9];
    const float* b_hh   = (const float*)d_in[10];
    const float* W_lin  = (const float*)d_in[11];
    const float* b_lin  = (const float*)d_in[12];
    float* out = (float*)d_out;

    int N = in_sizes[0] / F_IN;       // 65536
    int E = in_sizes[1] / 2;          // 1048576
    int Etot = E + N;                 // self-loops appended
    int B = N / T_SEQ;                // 32

    float* ws = (float*)d_ws;
    float* xp     = ws;                                   // N*64
    float* a_src  = xp + (size_t)N * 64;                  // N*8
    float* a_dst  = a_src + (size_t)N * 8;                // N*8
    float* denom  = a_dst + (size_t)N * 8;                // N*8
    float* agg    = denom + (size_t)N * 8;                // N*64
    float* gi     = agg + (size_t)N * 64;                 // N*48

    // zero denom + agg (contiguous): 2 + 16 MB
    hipMemsetAsync(denom, 0, (size_t)N * 72 * sizeof(float), stream);

    k1_xp<<<N / 4, 256, 0, stream>>>(x, W_gat, att_s, att_d, xp, a_src, a_dst);
    {
        long long tot = (long long)Etot * 64;
        int blocks = (int)((tot + 255) / 256);
        k4_agg<<<blocks, 256, 0, stream>>>(ei, E, Etot, a_src, a_dst, xp, denom, agg);
    }
    k5_gi<<<N / 16, 256, 0, stream>>>(agg, denom, b_gat, W_ih, b_ih, gi);
    k6_gru<<<B, 64, 0, stream>>>(gi, W_hh, b_hh, W_lin, b_lin, out, B);
}